// Round 9
// baseline (333.486 us; speedup 1.0000x reference)
//
#include <hip/hip_runtime.h>
#include <math.h>

static constexpr int B = 4, H = 160, W = 160;
static constexpr int HW = H * W;          // 25600
static constexpr int CHW = 64 * HW;       // 1638400
static constexpr int NELEM = B * CHW;     // 6553600

// padded grid for aspp GEMM view: 168x168 (halo 4) + guard slack
static constexpr int WP = 168;
static constexpr int HP = 168;
static constexpr int PHW = WP * HP;       // 28224
static constexpr int PGUARD = 704;        // front guard (>= 4*168+16)
static constexpr int PSTRIDE = 30720;     // per-b px stride
static constexpr int IMGOFS = PGUARD + 4 * WP + 4;  // = 1380, padded idx of (0,0)

typedef short bf16x8 __attribute__((ext_vector_type(8)));
typedef float f32x4 __attribute__((ext_vector_type(4)));

__device__ __forceinline__ float lrelu(float v) { return v >= 0.f ? v : 0.1f * v; }

__device__ __forceinline__ unsigned short f2bf(float f) {
  unsigned u = __float_as_uint(f);
  return (unsigned short)((u + 0x7FFFu + ((u >> 16) & 1u)) >> 16);  // RNE
}
__device__ __forceinline__ float bf2f(short u) {
  return __uint_as_float(((unsigned)(unsigned short)u) << 16);
}

__device__ __forceinline__ void glds16(const void* g, void* l) {
  __builtin_amdgcn_global_load_lds(
      (const __attribute__((address_space(1))) void*)g,
      (__attribute__((address_space(3))) void*)l, 16, 0, 0);
}

// ---------------------------------------------------------------------------
// Weight transforms + zero-fill of the padded input buffer (margins must be 0).
// ---------------------------------------------------------------------------
__global__ __launch_bounds__(256) void k_transform(
    const float* __restrict__ w01, const float* __restrict__ dw,
    const float* __restrict__ arw, const float* __restrict__ a1w,
    const float* __restrict__ a2w, const float* __restrict__ a3w,
    float* __restrict__ wt01, unsigned short* __restrict__ wb_bf,
    unsigned short* __restrict__ wd_bf, unsigned short* __restrict__ arw_bf,
    unsigned short* __restrict__ off0p) {
  int i = blockIdx.x * 256 + threadIdx.x;  // 0 .. 167935
  uint4* zp = (uint4*)off0p;
#pragma unroll
  for (int j = 0; j < 6; ++j) {
    unsigned u = (unsigned)i + (unsigned)j * 167936u;
    if (u < 983040u) zp[u] = make_uint4(0u, 0u, 0u, 0u);
  }
  if (i < 8192) {
    int ci = i >> 6, o = i & 63;
    wt01[i] = w01[o * 128 + ci];
  } else if (i < 118784) {
    int j = i - 8192;
    int ci = j & 63, co = (j >> 6) & 63;
    int kk = j >> 12;              // dsel*9 + k, 0..26
    int dsel = kk / 9; kk -= dsel * 9;
    const float* src = dsel == 0 ? a1w : dsel == 1 ? a2w : a3w;
    wb_bf[j] = f2bf(src[(co * 64 + ci) * 9 + kk]);
  } else if (i < 155648) {
    int j = i - 118784;
    int ci = j & 63, co = (j >> 6) & 63, k = j >> 12;  // k 0..8
    wd_bf[j] = f2bf(dw[(co * 64 + ci) * 9 + k]);
  } else if (i < 167936) {
    int j = i - 155648;
    arw_bf[j] = f2bf(arw[j]);  // already [o][cp]
  }
}

// ---------------------------------------------------------------------------
// Kernel A: 1x1 conv concat(aux,ref) 128->64 + bias + lrelu.
// Emits fp32 channel-major off0, bf16 PADDED pos-major off0p[ppos][ci], AND
// bf16 pos-major x_bf[pos][ci] (aux transpose, from the same LDS staging).
// grid: B*HW/64 = 1600
// ---------------------------------------------------------------------------
__global__ __launch_bounds__(256) void k_conv1x1_in(
    const float* __restrict__ aux, const float* __restrict__ ref,
    const float* __restrict__ wt01, const float* __restrict__ b01,
    float* __restrict__ out, unsigned short* __restrict__ off0p,
    unsigned short* __restrict__ x_bf) {
  __shared__ float s[128 * 64];  // 32 KB  s[ci*64+p]
  int pos0 = blockIdx.x * 64;
  int b = pos0 / HW;
  int hw0 = pos0 - b * HW;
  int tid = threadIdx.x;
  for (int i = tid; i < 8192; i += 256) {
    int ci = i >> 6, p = i & 63;
    const float* src = (ci < 64) ? (aux + b * CHW + ci * HW)
                                 : (ref + b * CHW + (ci - 64) * HW);
    s[i] = src[hw0 + p];
  }
  __syncthreads();
  int p = tid & 63;
  int g = __builtin_amdgcn_readfirstlane(tid >> 6);
  const float* wp = wt01 + g * 16;
  float acc[16];
#pragma unroll
  for (int j = 0; j < 16; ++j) acc[j] = 0.f;
#pragma unroll 4
  for (int ci = 0; ci < 128; ++ci) {
    float sv = s[ci * 64 + p];
    const float* wrow = wp + ci * 64;  // uniform, o-contiguous -> s_loads
#pragma unroll
    for (int j = 0; j < 16; ++j) acc[j] += sv * wrow[j];
  }
  const float* bb = b01 + g * 16;
  int obase = (b * 64 + g * 16) * HW + hw0 + p;
  unsigned short tb[16];
#pragma unroll
  for (int j = 0; j < 16; ++j) {
    float v = lrelu(acc[j] + bb[j]);
    out[obase + j * HW] = v;
    tb[j] = f2bf(v);
  }
  int hw = hw0 + p;
  int h = hw / W, w = hw - h * W;
  unsigned short* dst =
      off0p + ((size_t)b * PSTRIDE + IMGOFS + h * WP + w) * 64 + g * 16;
  *(uint4*)dst = *(const uint4*)&tb[0];
  *(uint4*)(dst + 8) = *(const uint4*)&tb[8];
  // x_bf: aux transpose from the staged LDS (rows 0..63 are aux)
  unsigned short xb[16];
#pragma unroll
  for (int j = 0; j < 16; ++j) xb[j] = f2bf(s[(g * 16 + j) * 64 + p]);
  unsigned short* xdst = x_bf + ((size_t)(b * HW + hw0 + p)) * 64 + g * 16;
  *(uint4*)xdst = *(const uint4*)&xb[0];
  *(uint4*)(xdst + 8) = *(const uint4*)&xb[8];
}

// ---------------------------------------------------------------------------
// Kernel B v5: padded-GEMM aspp, row-union staging + 2-phase pipeline + swz.
// (unchanged from R4)
// ---------------------------------------------------------------------------
__global__ __launch_bounds__(256) void k_aspp3_mfma(
    const unsigned short* __restrict__ off0p,
    const unsigned short* __restrict__ wb_bf,
    const float* __restrict__ a1b, const float* __restrict__ a2b,
    const float* __restrict__ a3b, unsigned short* __restrict__ r_bf) {
  __shared__ unsigned short sa[2][288 * 64];  // 2 x 36864 B
  int tid = threadIdx.x;
  int lane = tid & 63, wid = tid >> 6;
  int m = lane & 15, q = lane >> 4;

  // bijective XCD swizzle for nwg=1332 (q=166, r=4)
  int p0 = blockIdx.x;
  int xcd = p0 & 7, ii = p0 >> 3;
  int base = xcd < 4 ? xcd * 167 : 668 + (xcd - 4) * 166;
  int lid = base + ii;
  int dsel = lid % 3;
  int tj = lid / 3;
  int b = tj / 111;
  int tile = tj - b * 111;
  int pos0 = tile * 256;
  const int d = 1 << dsel;
  const unsigned short* pb = off0p + (size_t)b * PSTRIDE * 64;
  const float* bias = dsel == 0 ? a1b : dsel == 1 ? a2b : a3b;

  f32x4 acc[4][4] = {};

  auto STAGE = [&](int buf, int ky) {
    const char* src =
        (const char*)(pb + (size_t)(PGUARD + pos0 + (ky - 1) * d * WP - 16) * 64);
    char* dstb = (char*)&sa[buf][0];
#pragma unroll
    for (int r = 0; r < 9; ++r) {
      int X = r * 4096 + tid * 16;       // byte offset in window (linear dest)
      int row = X >> 7;                  // px index in window
      int Xs = X ^ ((row & 7) << 4);     // source permutation = read permutation
      glds16(src + Xs, dstb + X);
    }
  };
  auto COMPUTE = [&](int buf, int ky) {
    const char* sb = (const char*)&sa[buf][0];
#pragma unroll
    for (int kx = 0; kx < 3; ++kx) {
      const unsigned short* wk = wb_bf + (dsel * 9 + ky * 3 + kx) * 4096;
      int px0 = 16 + (kx - 1) * d + wid * 64;  // window-relative px, this wave
#pragma unroll
      for (int kc = 0; kc < 2; ++kc) {
        bf16x8 bfrag[4];
#pragma unroll
        for (int t = 0; t < 4; ++t)
          bfrag[t] = *(const bf16x8*)(wk + (t * 16 + m) * 64 + kc * 32 + q * 8);
#pragma unroll
        for (int mt = 0; mt < 4; ++mt) {
          int px = px0 + mt * 16 + m;
          int byteoff = px * 128 + ((kc * 64 + q * 16) ^ ((px & 7) << 4));
          bf16x8 afrag = *(const bf16x8*)(sb + byteoff);
#pragma unroll
          for (int t = 0; t < 4; ++t)
            acc[mt][t] = __builtin_amdgcn_mfma_f32_16x16x32_bf16(
                afrag, bfrag[t], acc[mt][t], 0, 0, 0);
        }
      }
    }
  };

  STAGE(0, 0);
  __syncthreads();            // vmcnt(0) drain + barrier (buf0 ready)
  STAGE(1, 1);                // prefetch row1 while computing row0
  COMPUTE(0, 0);
  __syncthreads();            // buf1 ready; buf0 reads done
  STAGE(0, 2);                // prefetch row2 while computing row1
  COMPUTE(1, 1);
  __syncthreads();            // buf0 ready; buf1 reads done
  COMPUTE(0, 2);

  // epilogue: bias + lrelu, pack bf16 via LDS (stride 68: v3-proven 0-conflict)
  __syncthreads();            // all buf0 reads done before ep overwrite
  unsigned short* epb = &sa[0][0];  // ep[pix*68 + co], 34816 B
#pragma unroll
  for (int t = 0; t < 4; ++t) {
    float bi = bias[t * 16 + m];
#pragma unroll
    for (int mt = 0; mt < 4; ++mt)
#pragma unroll
      for (int r = 0; r < 4; ++r)  // D: col=co (m), row=q*4+r (pixel)
        epb[(wid * 64 + mt * 16 + q * 4 + r) * 68 + t * 16 + m] =
            f2bf(lrelu(acc[mt][t][r] + bi));
  }
  __syncthreads();
  {
    int qa = pos0 + tid;  // padded position of this thread's pixel
    int pr = qa / WP, pc = qa - pr * WP;
    if (pr >= 4 && pr < 164 && pc >= 4 && pc < 164) {
      int hw = (pr - 4) * W + (pc - 4);
      unsigned short* dst = r_bf + ((size_t)(b * HW + hw)) * 192 + dsel * 64;
      const unsigned short* s2 = epb + tid * 68;
#pragma unroll
      for (int c = 0; c < 8; ++c)
        *(uint4*)(dst + c * 8) = *(const uint4*)(s2 + c * 8);
    }
  }
}

// ---------------------------------------------------------------------------
// Kernel C: MFMA merge 192->64 (+bias+residual) then offset head 64->18.
// grid: B*HW/64 = 1600
// ---------------------------------------------------------------------------
__global__ __launch_bounds__(256) void k_merge_head_mfma(
    const unsigned short* __restrict__ r_bf, const float* __restrict__ off0,
    const unsigned short* __restrict__ arw_bf, const float* __restrict__ arb,
    const float* __restrict__ w02, const float* __restrict__ b02,
    float* __restrict__ offs) {
  __shared__ unsigned short sa[64 * 200];  // 25600 B; reused as float ep[64*65]
  int pos0 = blockIdx.x * 64;
  int b = pos0 / HW;
  int hw0 = pos0 - b * HW;
  int tid = threadIdx.x;
  const unsigned short* gsrc = r_bf + (size_t)(b * HW + hw0) * 192;
  for (int i = tid; i < 1536; i += 256) {
    int pos = i / 24, c8 = i - pos * 24;
    *(uint4*)(sa + pos * 200 + c8 * 8) = *(const uint4*)(gsrc + i * 8);
  }
  __syncthreads();
  int lane = tid & 63, wid = tid >> 6;
  int m = lane & 15, q = lane >> 4;
  f32x4 acc[4] = {};
#pragma unroll
  for (int kc = 0; kc < 6; ++kc) {
    bf16x8 bfrag = *(const bf16x8*)(arw_bf + (wid * 16 + m) * 192 + kc * 32 + q * 8);
#pragma unroll
    for (int mt = 0; mt < 4; ++mt) {
      bf16x8 afrag = *(const bf16x8*)(sa + (mt * 16 + m) * 200 + kc * 32 + q * 8);
      acc[mt] = __builtin_amdgcn_mfma_f32_16x16x32_bf16(afrag, bfrag, acc[mt],
                                                        0, 0, 0);
    }
  }
  __syncthreads();  // all afrag reads done before overwriting sa
  float* ep = (float*)sa;  // ep[pos*65 + co]
  int co = wid * 16 + m;
  float bi = arb[co];
  const float* resrow = off0 + (size_t)(b * 64 + co) * HW + hw0;
#pragma unroll
  for (int mt = 0; mt < 4; ++mt)
#pragma unroll
    for (int r = 0; r < 4; ++r) {
      int pos = mt * 16 + q * 4 + r;  // D: col=co, row=pos
      ep[pos * 65 + co] = acc[mt][r] + bi + resrow[pos];
    }
  __syncthreads();
  for (int i = tid; i < 1152; i += 256) {
    int t = i >> 6, p = i & 63;
    const float* w2 = w02 + t * 64;  // t wave-uniform -> s_loads
    float o = b02[t];
#pragma unroll 8
    for (int c = 0; c < 64; ++c) o += ep[p * 65 + c] * w2[c];
    offs[(b * 18 + t) * HW + hw0 + p] = o;
  }
}

// ---------------------------------------------------------------------------
// Kernel E v5: sample-all-then-GEMM. The 9-round {gather->blend->LDS->
// barrier->MFMA} lockstep exposed gather latency 9x and convoyed waves at 9
// barriers (v1/v3/v4 all ~78-86us; in-wave reg-pipelining attempts undone by
// the allocator, VGPR=68/72 proofs). Now: block = 32 px; sample ALL 9 taps
// into one LDS im2col tile (row = tap*32+px, 128B rows, v4-proven XOR
// swizzle) -- 36 independent gathers/lane, ZERO barriers between them, so
// vmcnt-deep pipelining needs no persistent register sets. ONE barrier, then
// 36 MFMAs/wave. LDS 36864B -> 4 blocks/CU; co-resident blocks phase-shift
// (sample of one overlaps GEMM of another).
// grid: 3200 = B*HW/32 (= 8 x 400, exact XCD swizzle)  [R8 bug: was 1600]
// ---------------------------------------------------------------------------
__global__ __launch_bounds__(256) void k_deform_mfma(
    const unsigned short* __restrict__ x_bf, const float* __restrict__ offs,
    const unsigned short* __restrict__ wd_bf, const float* __restrict__ db,
    float* __restrict__ out) {
  __shared__ unsigned short smp[288 * 64];  // 36864 B: row = tap*32+px, 128B
  int blk = (blockIdx.x & 7) * 400 + (blockIdx.x >> 3);  // XCD slab swizzle
  int pos0 = blk * 32;
  int b = pos0 / HW;
  int hw0 = pos0 - b * HW;
  int tid = threadIdx.x;
  int lane = tid & 63, wid = tid >> 6;
  int m = lane & 15, q = lane >> 4;
  // sampling role: lane -> (px = lane&31, 8-ci slice = wid*16 + (lane>>5)*8)
  int sp = lane & 31;
  int ch8 = lane >> 5;
  int cbyte = wid * 32 + ch8 * 16;        // byte offset of slice within row
  int hw = hw0 + sp;
  int h = hw / W, wv = hw - h * W;
  const unsigned short* xbase = x_bf + (size_t)b * HW * 64 + wid * 16 + ch8 * 8;
  const float* ob = offs + b * 18 * HW + hw;
  float offv[18];
#pragma unroll
  for (int j = 0; j < 18; ++j) offv[j] = ob[j * HW];

  // ---- sample phase: 9 taps, no barriers, 36 independent gathers/lane ----
#pragma unroll
  for (int k = 0; k < 9; ++k) {
    const int ky = k / 3, kx = k - ky * 3;
    float py = offv[2 * k] + (float)(h - 1 + ky);
    float px = offv[2 * k + 1] + (float)(wv - 1 + kx);
    float fy = floorf(py), fx = floorf(px);
    int iy0 = (int)fy, ix0 = (int)fx;
    float wy = py - fy, wx = px - fx;
    int iy1 = iy0 + 1, ix1 = ix0 + 1;
    float vy0 = (iy0 >= 0 && iy0 < H) ? 1.f : 0.f;
    float vy1 = (iy1 >= 0 && iy1 < H) ? 1.f : 0.f;
    float vx0 = (ix0 >= 0 && ix0 < W) ? 1.f : 0.f;
    float vx1 = (ix1 >= 0 && ix1 < W) ? 1.f : 0.f;
    int cy0 = min(max(iy0, 0), H - 1), cy1 = min(max(iy1, 0), H - 1);
    int cx0 = min(max(ix0, 0), W - 1), cx1 = min(max(ix1, 0), W - 1);
    float c00 = vy0 * vx0 * (1.f - wy) * (1.f - wx);
    float c01 = vy0 * vx1 * (1.f - wy) * wx;
    float c10 = vy1 * vx0 * wy * (1.f - wx);
    float c11 = vy1 * vx1 * wy * wx;
    bf16x8 v00 = *(const bf16x8*)(xbase + (size_t)(cy0 * W + cx0) * 64);
    bf16x8 v01 = *(const bf16x8*)(xbase + (size_t)(cy0 * W + cx1) * 64);
    bf16x8 v10 = *(const bf16x8*)(xbase + (size_t)(cy1 * W + cx0) * 64);
    bf16x8 v11 = *(const bf16x8*)(xbase + (size_t)(cy1 * W + cx1) * 64);
    unsigned tw[4];
#pragma unroll
    for (int jj = 0; jj < 4; ++jj) {
      float s0 = c00 * bf2f(v00[2 * jj]) + c01 * bf2f(v01[2 * jj]) +
                 c10 * bf2f(v10[2 * jj]) + c11 * bf2f(v11[2 * jj]);
      float s1 = c00 * bf2f(v00[2 * jj + 1]) + c01 * bf2f(v01[2 * jj + 1]) +
                 c10 * bf2f(v10[2 * jj + 1]) + c11 * bf2f(v11[2 * jj + 1]);
      asm("v_cvt_pk_bf16_f32 %0, %1, %2" : "=v"(tw[jj]) : "v"(s0), "v"(s1));
    }
    int row = k * 32 + sp;
    char* dst = (char*)smp + row * 128 + (cbyte ^ ((row & 7) << 4));
    *(uint4*)dst = *(const uint4*)&tw[0];
  }
  __syncthreads();

  // ---- GEMM phase: 36 MFMAs/wave, wave = 16-co group x all 32 px ----
  f32x4 acc[2] = {};
#pragma unroll
  for (int k = 0; k < 9; ++k)
#pragma unroll
    for (int kc = 0; kc < 2; ++kc) {
      bf16x8 bfrag = *(const bf16x8*)(wd_bf + (k * 64 + wid * 16 + m) * 64 +
                                      kc * 32 + q * 8);
#pragma unroll
      for (int mt = 0; mt < 2; ++mt) {
        int row = k * 32 + mt * 16 + m;
        int off = (kc * 64 + q * 16) ^ ((row & 7) << 4);
        bf16x8 afrag = *(const bf16x8*)((const char*)smp + row * 128 + off);
        acc[mt] = __builtin_amdgcn_mfma_f32_16x16x32_bf16(afrag, bfrag, acc[mt],
                                                          0, 0, 0);
      }
    }

  int co = wid * 16 + m;
  float bias = db[co];
  size_t orow = (size_t)(b * 64 + co) * HW + hw0;
#pragma unroll
  for (int mt = 0; mt < 2; ++mt)
#pragma unroll
    for (int r = 0; r < 4; ++r)
      out[orow + mt * 16 + q * 4 + r] = acc[mt][r] + bias;  // D: col=co, row=px
}

// ---------------------------------------------------------------------------
extern "C" void kernel_launch(void* const* d_in, const int* in_sizes, int n_in,
                              void* d_out, int out_size, void* d_ws, size_t ws_size,
                              hipStream_t stream) {
  const float* aux = (const float*)d_in[0];
  const float* ref = (const float*)d_in[1];
  const float* w01 = (const float*)d_in[2];
  const float* b01 = (const float*)d_in[3];
  const float* a1w = (const float*)d_in[4];
  const float* a1b = (const float*)d_in[5];
  const float* a2w = (const float*)d_in[6];
  const float* a2b = (const float*)d_in[7];
  const float* a3w = (const float*)d_in[8];
  const float* a3b = (const float*)d_in[9];
  const float* arw = (const float*)d_in[10];
  const float* arb = (const float*)d_in[11];
  const float* w02 = (const float*)d_in[12];
  const float* b02 = (const float*)d_in[13];
  const float* dw  = (const float*)d_in[14];
  const float* db  = (const float*)d_in[15];
  float* out = (float*)d_out;

  float* off0 = (float*)d_ws;                        // [B,64,H,W] fp32
  float* offs = off0 + NELEM;                        // [B,18,H,W] fp32
  float* wt01 = offs + B * 18 * HW;                  // 8192 f32
  unsigned short* off0p = (unsigned short*)(wt01 + 8192);    // [B,PSTRIDE,64] bf16
  unsigned short* x_bf   = off0p + (size_t)B * PSTRIDE * 64; // [B,HW,64] bf16
  unsigned short* wb_bf  = x_bf + (size_t)NELEM;             // 110592 bf16
  unsigned short* wd_bf  = wb_bf + 110592;                   // 36864 bf16
  unsigned short* arw_bf = wd_bf + 36864;                    // 12288 bf16
  unsigned short* r_bf   = arw_bf + 12288;           // [B,HW,192] bf16

  k_transform<<<656, 256, 0, stream>>>(w01, dw, arw, a1w, a2w, a3w,
                                       wt01, wb_bf, wd_bf, arw_bf, off0p);
  k_conv1x1_in<<<B * HW / 64, 256, 0, stream>>>(aux, ref, wt01, b01, off0,
                                                off0p, x_bf);
  k_aspp3_mfma<<<1332, 256, 0, stream>>>(off0p, wb_bf, a1b, a2b, a3b, r_bf);
  k_merge_head_mfma<<<B * HW / 64, 256, 0, stream>>>(
      r_bf, off0, arw_bf, arb, w02, b02, offs);
  k_deform_mfma<<<B * HW / 32, 256, 0, stream>>>(x_bf, offs, wd_bf, db, out);
}

// Round 11
// 323.310 us; speedup vs baseline: 1.0315x; 1.0315x over previous
//
#include <hip/hip_runtime.h>
#include <math.h>

static constexpr int B = 4, H = 160, W = 160;
static constexpr int HW = H * W;          // 25600
static constexpr int CHW = 64 * HW;       // 1638400
static constexpr int NELEM = B * CHW;     // 6553600

// padded grid for aspp GEMM view: 168x168 (halo 4) + guard slack
static constexpr int WP = 168;
static constexpr int HP = 168;
static constexpr int PHW = WP * HP;       // 28224
static constexpr int PGUARD = 704;        // front guard (>= 4*168+16)
static constexpr int PSTRIDE = 30720;     // per-b px stride
static constexpr int IMGOFS = PGUARD + 4 * WP + 4;  // = 1380, padded idx of (0,0)

typedef short bf16x8 __attribute__((ext_vector_type(8)));
typedef float f32x4 __attribute__((ext_vector_type(4)));

__device__ __forceinline__ float lrelu(float v) { return v >= 0.f ? v : 0.1f * v; }

__device__ __forceinline__ unsigned short f2bf(float f) {
  unsigned u = __float_as_uint(f);
  return (unsigned short)((u + 0x7FFFu + ((u >> 16) & 1u)) >> 16);  // RNE
}
__device__ __forceinline__ float bf2f(short u) {
  return __uint_as_float(((unsigned)(unsigned short)u) << 16);
}

__device__ __forceinline__ void glds16(const void* g, void* l) {
  __builtin_amdgcn_global_load_lds(
      (const __attribute__((address_space(1))) void*)g,
      (__attribute__((address_space(3))) void*)l, 16, 0, 0);
}

// ---------------------------------------------------------------------------
// Weight transforms + zero-fill of the padded input buffer (margins must be 0).
// ---------------------------------------------------------------------------
__global__ __launch_bounds__(256) void k_transform(
    const float* __restrict__ w01, const float* __restrict__ dw,
    const float* __restrict__ arw, const float* __restrict__ a1w,
    const float* __restrict__ a2w, const float* __restrict__ a3w,
    float* __restrict__ wt01, unsigned short* __restrict__ wb_bf,
    unsigned short* __restrict__ wd_bf, unsigned short* __restrict__ arw_bf,
    unsigned short* __restrict__ off0p) {
  int i = blockIdx.x * 256 + threadIdx.x;  // 0 .. 167935
  uint4* zp = (uint4*)off0p;
#pragma unroll
  for (int j = 0; j < 6; ++j) {
    unsigned u = (unsigned)i + (unsigned)j * 167936u;
    if (u < 983040u) zp[u] = make_uint4(0u, 0u, 0u, 0u);
  }
  if (i < 8192) {
    int ci = i >> 6, o = i & 63;
    wt01[i] = w01[o * 128 + ci];
  } else if (i < 118784) {
    int j = i - 8192;
    int ci = j & 63, co = (j >> 6) & 63;
    int kk = j >> 12;              // dsel*9 + k, 0..26
    int dsel = kk / 9; kk -= dsel * 9;
    const float* src = dsel == 0 ? a1w : dsel == 1 ? a2w : a3w;
    wb_bf[j] = f2bf(src[(co * 64 + ci) * 9 + kk]);
  } else if (i < 155648) {
    int j = i - 118784;
    int ci = j & 63, co = (j >> 6) & 63, k = j >> 12;  // k 0..8
    wd_bf[j] = f2bf(dw[(co * 64 + ci) * 9 + k]);
  } else if (i < 167936) {
    int j = i - 155648;
    arw_bf[j] = f2bf(arw[j]);  // already [o][cp]
  }
}

// ---------------------------------------------------------------------------
// Kernel A: 1x1 conv concat(aux,ref) 128->64 + bias + lrelu.
// Emits fp32 channel-major off0, bf16 PADDED pos-major off0p[ppos][ci], AND
// bf16 pos-major x_bf[pos][ci] (aux transpose, from the same LDS staging).
// grid: B*HW/64 = 1600
// ---------------------------------------------------------------------------
__global__ __launch_bounds__(256) void k_conv1x1_in(
    const float* __restrict__ aux, const float* __restrict__ ref,
    const float* __restrict__ wt01, const float* __restrict__ b01,
    float* __restrict__ out, unsigned short* __restrict__ off0p,
    unsigned short* __restrict__ x_bf) {
  __shared__ float s[128 * 64];  // 32 KB  s[ci*64+p]
  int pos0 = blockIdx.x * 64;
  int b = pos0 / HW;
  int hw0 = pos0 - b * HW;
  int tid = threadIdx.x;
  for (int i = tid; i < 8192; i += 256) {
    int ci = i >> 6, p = i & 63;
    const float* src = (ci < 64) ? (aux + b * CHW + ci * HW)
                                 : (ref + b * CHW + (ci - 64) * HW);
    s[i] = src[hw0 + p];
  }
  __syncthreads();
  int p = tid & 63;
  int g = __builtin_amdgcn_readfirstlane(tid >> 6);
  const float* wp = wt01 + g * 16;
  float acc[16];
#pragma unroll
  for (int j = 0; j < 16; ++j) acc[j] = 0.f;
#pragma unroll 4
  for (int ci = 0; ci < 128; ++ci) {
    float sv = s[ci * 64 + p];
    const float* wrow = wp + ci * 64;  // uniform, o-contiguous -> s_loads
#pragma unroll
    for (int j = 0; j < 16; ++j) acc[j] += sv * wrow[j];
  }
  const float* bb = b01 + g * 16;
  int obase = (b * 64 + g * 16) * HW + hw0 + p;
  unsigned short tb[16];
#pragma unroll
  for (int j = 0; j < 16; ++j) {
    float v = lrelu(acc[j] + bb[j]);
    out[obase + j * HW] = v;
    tb[j] = f2bf(v);
  }
  int hw = hw0 + p;
  int h = hw / W, w = hw - h * W;
  unsigned short* dst =
      off0p + ((size_t)b * PSTRIDE + IMGOFS + h * WP + w) * 64 + g * 16;
  *(uint4*)dst = *(const uint4*)&tb[0];
  *(uint4*)(dst + 8) = *(const uint4*)&tb[8];
  // x_bf: aux transpose from the staged LDS (rows 0..63 are aux)
  unsigned short xb[16];
#pragma unroll
  for (int j = 0; j < 16; ++j) xb[j] = f2bf(s[(g * 16 + j) * 64 + p]);
  unsigned short* xdst = x_bf + ((size_t)(b * HW + hw0 + p)) * 64 + g * 16;
  *(uint4*)xdst = *(const uint4*)&xb[0];
  *(uint4*)(xdst + 8) = *(const uint4*)&xb[8];
}

// ---------------------------------------------------------------------------
// Kernel B v5: padded-GEMM aspp, row-union staging + 2-phase pipeline + swz.
// (R4 structure; + T5 setprio around MFMA clusters)
// ---------------------------------------------------------------------------
__global__ __launch_bounds__(256) void k_aspp3_mfma(
    const unsigned short* __restrict__ off0p,
    const unsigned short* __restrict__ wb_bf,
    const float* __restrict__ a1b, const float* __restrict__ a2b,
    const float* __restrict__ a3b, unsigned short* __restrict__ r_bf) {
  __shared__ unsigned short sa[2][288 * 64];  // 2 x 36864 B
  int tid = threadIdx.x;
  int lane = tid & 63, wid = tid >> 6;
  int m = lane & 15, q = lane >> 4;

  // bijective XCD swizzle for nwg=1332 (q=166, r=4)
  int p0 = blockIdx.x;
  int xcd = p0 & 7, ii = p0 >> 3;
  int base = xcd < 4 ? xcd * 167 : 668 + (xcd - 4) * 166;
  int lid = base + ii;
  int dsel = lid % 3;
  int tj = lid / 3;
  int b = tj / 111;
  int tile = tj - b * 111;
  int pos0 = tile * 256;
  const int d = 1 << dsel;
  const unsigned short* pb = off0p + (size_t)b * PSTRIDE * 64;
  const float* bias = dsel == 0 ? a1b : dsel == 1 ? a2b : a3b;

  f32x4 acc[4][4] = {};

  auto STAGE = [&](int buf, int ky) {
    const char* src =
        (const char*)(pb + (size_t)(PGUARD + pos0 + (ky - 1) * d * WP - 16) * 64);
    char* dstb = (char*)&sa[buf][0];
#pragma unroll
    for (int r = 0; r < 9; ++r) {
      int X = r * 4096 + tid * 16;       // byte offset in window (linear dest)
      int row = X >> 7;                  // px index in window
      int Xs = X ^ ((row & 7) << 4);     // source permutation = read permutation
      glds16(src + Xs, dstb + X);
    }
  };
  auto COMPUTE = [&](int buf, int ky) {
    const char* sb = (const char*)&sa[buf][0];
    __builtin_amdgcn_s_setprio(1);
#pragma unroll
    for (int kx = 0; kx < 3; ++kx) {
      const unsigned short* wk = wb_bf + (dsel * 9 + ky * 3 + kx) * 4096;
      int px0 = 16 + (kx - 1) * d + wid * 64;  // window-relative px, this wave
#pragma unroll
      for (int kc = 0; kc < 2; ++kc) {
        bf16x8 bfrag[4];
#pragma unroll
        for (int t = 0; t < 4; ++t)
          bfrag[t] = *(const bf16x8*)(wk + (t * 16 + m) * 64 + kc * 32 + q * 8);
#pragma unroll
        for (int mt = 0; mt < 4; ++mt) {
          int px = px0 + mt * 16 + m;
          int byteoff = px * 128 + ((kc * 64 + q * 16) ^ ((px & 7) << 4));
          bf16x8 afrag = *(const bf16x8*)(sb + byteoff);
#pragma unroll
          for (int t = 0; t < 4; ++t)
            acc[mt][t] = __builtin_amdgcn_mfma_f32_16x16x32_bf16(
                afrag, bfrag[t], acc[mt][t], 0, 0, 0);
        }
      }
    }
    __builtin_amdgcn_s_setprio(0);
  };

  STAGE(0, 0);
  __syncthreads();            // vmcnt(0) drain + barrier (buf0 ready)
  STAGE(1, 1);                // prefetch row1 while computing row0
  COMPUTE(0, 0);
  __syncthreads();            // buf1 ready; buf0 reads done
  STAGE(0, 2);                // prefetch row2 while computing row1
  COMPUTE(1, 1);
  __syncthreads();            // buf0 ready; buf1 reads done
  COMPUTE(0, 2);

  // epilogue: bias + lrelu, pack bf16 via LDS (stride 68: v3-proven 0-conflict)
  __syncthreads();            // all buf0 reads done before ep overwrite
  unsigned short* epb = &sa[0][0];  // ep[pix*68 + co], 34816 B
#pragma unroll
  for (int t = 0; t < 4; ++t) {
    float bi = bias[t * 16 + m];
#pragma unroll
    for (int mt = 0; mt < 4; ++mt)
#pragma unroll
      for (int r = 0; r < 4; ++r)  // D: col=co (m), row=q*4+r (pixel)
        epb[(wid * 64 + mt * 16 + q * 4 + r) * 68 + t * 16 + m] =
            f2bf(lrelu(acc[mt][t][r] + bi));
  }
  __syncthreads();
  {
    int qa = pos0 + tid;  // padded position of this thread's pixel
    int pr = qa / WP, pc = qa - pr * WP;
    if (pr >= 4 && pr < 164 && pc >= 4 && pc < 164) {
      int hw = (pr - 4) * W + (pc - 4);
      unsigned short* dst = r_bf + ((size_t)(b * HW + hw)) * 192 + dsel * 64;
      const unsigned short* s2 = epb + tid * 68;
#pragma unroll
      for (int c = 0; c < 8; ++c)
        *(uint4*)(dst + c * 8) = *(const uint4*)(s2 + c * 8);
    }
  }
}

// ---------------------------------------------------------------------------
// Kernel C: MFMA merge 192->64 (+bias+residual) then offset head 64->18.
// grid: B*HW/64 = 1600
// ---------------------------------------------------------------------------
__global__ __launch_bounds__(256) void k_merge_head_mfma(
    const unsigned short* __restrict__ r_bf, const float* __restrict__ off0,
    const unsigned short* __restrict__ arw_bf, const float* __restrict__ arb,
    const float* __restrict__ w02, const float* __restrict__ b02,
    float* __restrict__ offs) {
  __shared__ unsigned short sa[64 * 200];  // 25600 B; reused as float ep[64*65]
  int pos0 = blockIdx.x * 64;
  int b = pos0 / HW;
  int hw0 = pos0 - b * HW;
  int tid = threadIdx.x;
  const unsigned short* gsrc = r_bf + (size_t)(b * HW + hw0) * 192;
  for (int i = tid; i < 1536; i += 256) {
    int pos = i / 24, c8 = i - pos * 24;
    *(uint4*)(sa + pos * 200 + c8 * 8) = *(const uint4*)(gsrc + i * 8);
  }
  __syncthreads();
  int lane = tid & 63, wid = tid >> 6;
  int m = lane & 15, q = lane >> 4;
  f32x4 acc[4] = {};
#pragma unroll
  for (int kc = 0; kc < 6; ++kc) {
    bf16x8 bfrag = *(const bf16x8*)(arw_bf + (wid * 16 + m) * 192 + kc * 32 + q * 8);
#pragma unroll
    for (int mt = 0; mt < 4; ++mt) {
      bf16x8 afrag = *(const bf16x8*)(sa + (mt * 16 + m) * 200 + kc * 32 + q * 8);
      acc[mt] = __builtin_amdgcn_mfma_f32_16x16x32_bf16(afrag, bfrag, acc[mt],
                                                        0, 0, 0);
    }
  }
  __syncthreads();  // all afrag reads done before overwriting sa
  float* ep = (float*)sa;  // ep[pos*65 + co]
  int co = wid * 16 + m;
  float bi = arb[co];
  const float* resrow = off0 + (size_t)(b * 64 + co) * HW + hw0;
#pragma unroll
  for (int mt = 0; mt < 4; ++mt)
#pragma unroll
    for (int r = 0; r < 4; ++r) {
      int pos = mt * 16 + q * 4 + r;  // D: col=co, row=pos
      ep[pos * 65 + co] = acc[mt][r] + bi + resrow[pos];
    }
  __syncthreads();
  for (int i = tid; i < 1152; i += 256) {
    int t = i >> 6, p = i & 63;
    const float* w2 = w02 + t * 64;  // t wave-uniform -> s_loads
    float o = b02[t];
#pragma unroll 8
    for (int c = 0; c < 64; ++c) o += ep[p * 65 + c] * w2[c];
    offs[(b * 18 + t) * HW + hw0 + p] = o;
  }
}

// ---------------------------------------------------------------------------
// Kernel E v8: v4's proven skeleton (XOR swizzle both sides, raw s_barrier +
// lgkmcnt(0), no vmcnt drain at barriers) + TAP-PAIRING: 2 taps per barrier
// round. Both taps' 16 gathers issue together (deeper MLP even if the
// allocator partially serializes); ONE barrier covers 16 MFMAs (was 8).
// Barriers 9 -> 5. Buffer sb[r&1] rewritten two rounds later with a barrier
// between (v4's exact spacing). T5 setprio around the MFMA cluster
// (2 blocks/CU -> cross-block phase diversity, the attn-positive regime).
// grid: 1600
// ---------------------------------------------------------------------------
__global__ __launch_bounds__(256) void k_deform_mfma(
    const unsigned short* __restrict__ x_bf, const float* __restrict__ offs,
    const unsigned short* __restrict__ wd_bf, const float* __restrict__ db,
    float* __restrict__ out) {
  __shared__ unsigned short sb[2][2][64 * 64];  // 2 bufs x 2 taps x 8 KB = 32 KB
  int blk = (blockIdx.x & 7) * 200 + (blockIdx.x >> 3);  // XCD slab swizzle
  int pos0 = blk * 64;
  int b = pos0 / HW;
  int hw0 = pos0 - b * HW;
  int tid = threadIdx.x;
  int lane = tid & 63, wid = tid >> 6;
  int m = lane & 15, q = lane >> 4;
  int p = lane;          // sampling position
  int cg = wid;          // sampling ci-group (16 ci)
  int hw = hw0 + p;
  int h = hw / W, wv = hw - h * W;
  const unsigned short* xbase = x_bf + (size_t)b * HW * 64;
  const float* ob = offs + b * 18 * HW + hw;
  float offv[18];
#pragma unroll
  for (int j = 0; j < 18; ++j) offv[j] = ob[j * HW];
  f32x4 acc[4] = {};

  // gather + bilinear blend + swizzled ds_write of tap k into dstbase
  auto SAMPLE = [&](int k, unsigned short* dstbase) {
    const int ky = k / 3, kx = k - ky * 3;
    float py = offv[2 * k] + (float)(h - 1 + ky);
    float pxf = offv[2 * k + 1] + (float)(wv - 1 + kx);
    float fy = floorf(py), fx = floorf(pxf);
    int iy0 = (int)fy, ix0 = (int)fx;
    float wy = py - fy, wx = pxf - fx;
    int iy1 = iy0 + 1, ix1 = ix0 + 1;
    float vy0 = (iy0 >= 0 && iy0 < H) ? 1.f : 0.f;
    float vy1 = (iy1 >= 0 && iy1 < H) ? 1.f : 0.f;
    float vx0 = (ix0 >= 0 && ix0 < W) ? 1.f : 0.f;
    float vx1 = (ix1 >= 0 && ix1 < W) ? 1.f : 0.f;
    int cy0 = min(max(iy0, 0), H - 1), cy1 = min(max(iy1, 0), H - 1);
    int cx0 = min(max(ix0, 0), W - 1), cx1 = min(max(ix1, 0), W - 1);
    float c00 = vy0 * vx0 * (1.f - wy) * (1.f - wx);
    float c01 = vy0 * vx1 * (1.f - wy) * wx;
    float c10 = vy1 * vx0 * wy * (1.f - wx);
    float c11 = vy1 * vx1 * wy * wx;
    const unsigned short* p00 = xbase + (size_t)(cy0 * W + cx0) * 64 + cg * 16;
    const unsigned short* p01 = xbase + (size_t)(cy0 * W + cx1) * 64 + cg * 16;
    const unsigned short* p10 = xbase + (size_t)(cy1 * W + cx0) * 64 + cg * 16;
    const unsigned short* p11 = xbase + (size_t)(cy1 * W + cx1) * 64 + cg * 16;
    unsigned tw0[4], tw1[4];
#pragma unroll
    for (int c2 = 0; c2 < 2; ++c2) {
      bf16x8 v00 = *(const bf16x8*)(p00 + c2 * 8);
      bf16x8 v01 = *(const bf16x8*)(p01 + c2 * 8);
      bf16x8 v10 = *(const bf16x8*)(p10 + c2 * 8);
      bf16x8 v11 = *(const bf16x8*)(p11 + c2 * 8);
      unsigned* tw = c2 ? tw1 : tw0;
#pragma unroll
      for (int jj = 0; jj < 4; ++jj) {
        float s0 = c00 * bf2f(v00[2 * jj]) + c01 * bf2f(v01[2 * jj]) +
                   c10 * bf2f(v10[2 * jj]) + c11 * bf2f(v11[2 * jj]);
        float s1 = c00 * bf2f(v00[2 * jj + 1]) + c01 * bf2f(v01[2 * jj + 1]) +
                   c10 * bf2f(v10[2 * jj + 1]) + c11 * bf2f(v11[2 * jj + 1]);
        asm("v_cvt_pk_bf16_f32 %0, %1, %2" : "=v"(tw[jj]) : "v"(s0), "v"(s1));
      }
    }
    char* wbase = (char*)dstbase + p * 128;
    *(uint4*)(wbase + ((cg * 32) ^ ((p & 7) << 4))) = *(const uint4*)&tw0[0];
    *(uint4*)(wbase + ((cg * 32 + 16) ^ ((p & 7) << 4))) = *(const uint4*)&tw1[0];
  };
  auto GEMM_TAP = [&](int k, const unsigned short* basep) {
#pragma unroll
    for (int kc = 0; kc < 2; ++kc) {
      bf16x8 bfrag =
          *(const bf16x8*)(wd_bf + (k * 64 + wid * 16 + m) * 64 + kc * 32 + q * 8);
#pragma unroll
      for (int mt = 0; mt < 4; ++mt) {
        int row = mt * 16 + m;
        int off = (kc * 64 + q * 16) ^ ((row & 7) << 4);  // same involution
        bf16x8 afrag = *(const bf16x8*)((const char*)basep + row * 128 + off);
        acc[mt] = __builtin_amdgcn_mfma_f32_16x16x32_bf16(afrag, bfrag, acc[mt],
                                                          0, 0, 0);
      }
    }
  };

#pragma unroll
  for (int r = 0; r < 4; ++r) {
    SAMPLE(2 * r, &sb[r & 1][0][0]);
    SAMPLE(2 * r + 1, &sb[r & 1][1][0]);
    __builtin_amdgcn_sched_barrier(0);
    asm volatile("s_waitcnt lgkmcnt(0)" ::: "memory");
    __builtin_amdgcn_s_barrier();
    __builtin_amdgcn_sched_barrier(0);
    __builtin_amdgcn_s_setprio(1);
    GEMM_TAP(2 * r, &sb[r & 1][0][0]);
    GEMM_TAP(2 * r + 1, &sb[r & 1][1][0]);
    __builtin_amdgcn_s_setprio(0);
  }
  // tap 8 (round 4, buf 0 half 0 -- last read at round 2; round 3's barrier
  // separates those reads from these writes, same spacing as the loop)
  SAMPLE(8, &sb[0][0][0]);
  __builtin_amdgcn_sched_barrier(0);
  asm volatile("s_waitcnt lgkmcnt(0)" ::: "memory");
  __builtin_amdgcn_s_barrier();
  __builtin_amdgcn_sched_barrier(0);
  __builtin_amdgcn_s_setprio(1);
  GEMM_TAP(8, &sb[0][0][0]);
  __builtin_amdgcn_s_setprio(0);

  int co = wid * 16 + m;
  float bias = db[co];
  size_t orow = (size_t)(b * 64 + co) * HW + hw0;
#pragma unroll
  for (int mt = 0; mt < 4; ++mt)
#pragma unroll
    for (int r = 0; r < 4; ++r)
      out[orow + mt * 16 + q * 4 + r] = acc[mt][r] + bias;  // D: col=co, row=pos
}

// ---------------------------------------------------------------------------
extern "C" void kernel_launch(void* const* d_in, const int* in_sizes, int n_in,
                              void* d_out, int out_size, void* d_ws, size_t ws_size,
                              hipStream_t stream) {
  const float* aux = (const float*)d_in[0];
  const float* ref = (const float*)d_in[1];
  const float* w01 = (const float*)d_in[2];
  const float* b01 = (const float*)d_in[3];
  const float* a1w = (const float*)d_in[4];
  const float* a1b = (const float*)d_in[5];
  const float* a2w = (const float*)d_in[6];
  const float* a2b = (const float*)d_in[7];
  const float* a3w = (const float*)d_in[8];
  const float* a3b = (const float*)d_in[9];
  const float* arw = (const float*)d_in[10];
  const float* arb = (const float*)d_in[11];
  const float* w02 = (const float*)d_in[12];
  const float* b02 = (const float*)d_in[13];
  const float* dw  = (const float*)d_in[14];
  const float* db  = (const float*)d_in[15];
  float* out = (float*)d_out;

  float* off0 = (float*)d_ws;                        // [B,64,H,W] fp32
  float* offs = off0 + NELEM;                        // [B,18,H,W] fp32
  float* wt01 = offs + B * 18 * HW;                  // 8192 f32
  unsigned short* off0p = (unsigned short*)(wt01 + 8192);    // [B,PSTRIDE,64] bf16
  unsigned short* x_bf   = off0p + (size_t)B * PSTRIDE * 64; // [B,HW,64] bf16
  unsigned short* wb_bf  = x_bf + (size_t)NELEM;             // 110592 bf16
  unsigned short* wd_bf  = wb_bf + 110592;                   // 36864 bf16
  unsigned short* arw_bf = wd_bf + 36864;                    // 12288 bf16
  unsigned short* r_bf   = arw_bf + 12288;           // [B,HW,192] bf16

  k_transform<<<656, 256, 0, stream>>>(w01, dw, arw, a1w, a2w, a3w,
                                       wt01, wb_bf, wd_bf, arw_bf, off0p);
  k_conv1x1_in<<<B * HW / 64, 256, 0, stream>>>(aux, ref, wt01, b01, off0,
                                                off0p, x_bf);
  k_aspp3_mfma<<<1332, 256, 0, stream>>>(off0p, wb_bf, a1b, a2b, a3b, r_bf);
  k_merge_head_mfma<<<B * HW / 64, 256, 0, stream>>>(
      r_bf, off0, arw_bf, arb, w02, b02, offs);
  k_deform_mfma<<<B * HW / 64, 256, 0, stream>>>(x_bf, offs, wd_bf, db, out);
}